// Round 10
// baseline (149.917 us; speedup 1.0000x reference)
//
#include <hip/hip_runtime.h>

static constexpr int kN   = 50000;    // nodes
static constexpr int kNR  = 100000;   // N*D rows
static constexpr int kE0  = 200000;   // original edges
static constexpr int kE2  = 400000;   // directed edges
static constexpr int kCAP = 32;       // adjacency capacity per node (Poisson(8): P(>=32)~7e-11)

typedef _Float16 f16;
typedef f16   f16x8 __attribute__((ext_vector_type(8)));
typedef f16   f16x4 __attribute__((ext_vector_type(4)));
typedef float f32x4 __attribute__((ext_vector_type(4)));

// ---------------------------------------------------------------------------
// k_wrh: one-shot fp32 -> f16 conversion of W_right (128x128, L2-resident)
// ---------------------------------------------------------------------------
__global__ __launch_bounds__(256) void k_wrh(
    const float* __restrict__ Wr, f16* __restrict__ Wrh)
{
    const int i = blockIdx.x * 256 + threadIdx.x;   // 16384 elements
    Wrh[i] = (f16)Wr[i];
}

// ---------------------------------------------------------------------------
// k_ab: one wave per node. lane l loads x_maps[n][4l..4l+3] (coalesced 1KB),
// 4 dot-partials vs W_sheaf rows, 6-level butterfly. No LDS, low VGPR ->
// high occupancy hides the shuffle latency chain (the round-9 k_node stall).
// ---------------------------------------------------------------------------
__global__ __launch_bounds__(256) void k_ab(
    const float* __restrict__ x, const float* __restrict__ Wsh,
    float4* __restrict__ ab)
{
    const int node = blockIdx.x * 4 + (threadIdx.x >> 6);
    const int lane = threadIdx.x & 63;
    const float4 xv  = *(const float4*)(x + (size_t)node * 256 + lane * 4);
    const float4 wa0 = *(const float4*)(Wsh + lane * 4);
    const float4 wb0 = *(const float4*)(Wsh + 256 + lane * 4);
    const float4 wa1 = *(const float4*)(Wsh + 512 + lane * 4);
    const float4 wb1 = *(const float4*)(Wsh + 768 + lane * 4);
    float pa0 = xv.x*wa0.x + xv.y*wa0.y + xv.z*wa0.z + xv.w*wa0.w;
    float pa1 = xv.x*wa1.x + xv.y*wa1.y + xv.z*wa1.z + xv.w*wa1.w;
    float pb0 = xv.x*wb0.x + xv.y*wb0.y + xv.z*wb0.z + xv.w*wb0.w;
    float pb1 = xv.x*wb1.x + xv.y*wb1.y + xv.z*wb1.z + xv.w*wb1.w;
    #pragma unroll
    for (int o = 32; o > 0; o >>= 1) {
        pa0 += __shfl_xor(pa0, o);
        pa1 += __shfl_xor(pa1, o);
        pb0 += __shfl_xor(pb0, o);
        pb1 += __shfl_xor(pb1, o);
    }
    if (lane == 0) ab[node] = make_float4(pa0, pa1, pb0, pb1);
}

// ---------------------------------------------------------------------------
// k_node: per block = 32 nodes (64 rows).
//  - tmp = W_left-mix of x (per row) -> LDS fp16 via packed ds_write_b64
//  - GEMM with SWAPPED operands: mfma(Wr_frag, tmp_frag) -> lane holds 4
//    CONSECUTIVE c of one node-row -> direct packed f16x4 global store
//    (no repack phase, single barrier)
// ---------------------------------------------------------------------------
__global__ __launch_bounds__(256) void k_node(
    const float* __restrict__ x, const float* __restrict__ Wl,
    const f16* __restrict__ Wrh, f16* __restrict__ xb)
{
    __shared__ f16 Al[64][136];    // tmp rows (+8 pad)

    const int t   = threadIdx.x;
    const int blk = blockIdx.x;

    const float wl00 = Wl[0], wl01 = Wl[1], wl10 = Wl[2], wl11 = Wl[3];
    const int w = t >> 6, lane = t & 63;

    // stage tmp into LDS (packed b64 writes)
    #pragma unroll
    for (int i = 0; i < 8; ++i) {
        const int f4   = i * 256 + t;        // float4 index in 64x128 tile
        const int row  = f4 >> 5;            // 0..63
        const int h4   = (f4 & 31) << 2;     // 0..124
        const int grow = blk * 64 + row;
        float4 xo = make_float4(0.f, 0.f, 0.f, 0.f);
        float4 xp = xo;
        if (grow < kNR) {
            xo = *(const float4*)(x + (size_t)grow * 128 + h4);
            xp = *(const float4*)(x + (size_t)(grow ^ 1) * 128 + h4);
        }
        const int dp = row & 1;
        const float  c0 = dp ? wl10 : wl00;
        const float  c1 = dp ? wl11 : wl01;
        const float4 x0 = dp ? xp : xo;      // d2 = 0 data
        const float4 x1 = dp ? xo : xp;      // d2 = 1 data
        f16x4 tv;
        tv[0] = (f16)(c0 * x0.x + c1 * x1.x);
        tv[1] = (f16)(c0 * x0.y + c1 * x1.y);
        tv[2] = (f16)(c0 * x0.z + c1 * x1.z);
        tv[3] = (f16)(c0 * x0.w + c1 * x1.w);
        *(f16x4*)&Al[row][h4] = tv;
    }
    __syncthreads();

    // MFMA, swapped operands: A = Wr rows (c), B = tmp rows (node-rows)
    const int lr = lane & 15, lk = lane >> 4;
    f16x8 tfr[4];
    #pragma unroll
    for (int kk = 0; kk < 4; ++kk)
        tfr[kk] = *(const f16x8*)&Al[16 * w + lr][kk * 32 + lk * 8];

    const int grow = blk * 64 + 16 * w + lr;   // node-row this lane outputs
    #pragma unroll
    for (int j = 0; j < 8; ++j) {
        f32x4 acc = {0.f, 0.f, 0.f, 0.f};
        #pragma unroll
        for (int kk = 0; kk < 4; ++kk) {
            const f16x8 wfr = *(const f16x8*)(Wrh + (size_t)(j * 16 + lr) * 128 + kk * 32 + lk * 8);
            acc = __builtin_amdgcn_mfma_f32_16x16x32_f16(wfr, tfr[kk], acc, 0, 0, 0);
        }
        // lane holds c = j*16 + lk*4 + r for node-row grow
        f16x4 ov;
        ov[0] = (f16)(-acc[0]); ov[1] = (f16)(-acc[1]);
        ov[2] = (f16)(-acc[2]); ov[3] = (f16)(-acc[3]);
        if (grow < kNR)
            *(f16x4*)(xb + (size_t)grow * 128 + j * 16 + lk * 4) = ov;
    }
}

// ---------------------------------------------------------------------------
// k_edge1: per DIRECTED edge j in [0,2*E0): maps2[j] = tanh(a[row]+b[col]),
// adjacency append (1 atomic per directed edge; no diag atomics).
// ---------------------------------------------------------------------------
__global__ __launch_bounds__(256) void k_edge1(
    const int* __restrict__ src, const int* __restrict__ dst,
    const float4* __restrict__ ab, float2* __restrict__ maps2,
    int* __restrict__ cnt, int2* __restrict__ adj)
{
    const int j = blockIdx.x * 256 + threadIdx.x;
    if (j >= kE2) return;
    const bool fwd = j < kE0;
    const int o = fwd ? j : j - kE0;
    const int s = src[o], d = dst[o];
    const int row = fwd ? s : d;
    const int col = fwd ? d : s;
    const float4 ar = ab[row], ac = ab[col];
    const float m0 = tanhf(ar.x + ac.z);
    const float m1 = tanhf(ar.y + ac.w);
    maps2[j] = make_float2(m0, m1);
    const int p = atomicAdd(&cnt[row], 1);
    if (p < kCAP) adj[(size_t)row * kCAP + p] = make_int2(j, col);
}

// ---------------------------------------------------------------------------
// k_diag: per node, walk adjacency, gather maps2, sum m^2 (no atomics).
// Also PADS the adjacency list to a multiple of 8 with sentinel
// (kE2, self) so k_gather runs mask-free (off[kE0] = 0 kills the term).
// ---------------------------------------------------------------------------
__global__ __launch_bounds__(256) void k_diag(
    const int* __restrict__ cnt, int2* __restrict__ adj,
    const float2* __restrict__ maps2, float2* __restrict__ diag)
{
    const int n = blockIdx.x * 256 + threadIdx.x;
    if (n >= kN) return;
    int c = cnt[n];
    if (c > kCAP) c = kCAP;
    int2* al = adj + (size_t)n * kCAP;
    float s0 = 0.f, s1 = 0.f;
    for (int k = 0; k < c; k += 4) {
        const int4 ea = *(const int4*)(al + k);
        const int4 eb = *(const int4*)(al + k + 2);
        const bool v1 = (k + 1 < c), v2 = (k + 2 < c), v3 = (k + 3 < c);
        const int j0 = ea.x;
        const int j1 = v1 ? ea.z : ea.x;
        const int j2 = v2 ? eb.x : ea.x;
        const int j3 = v3 ? eb.z : ea.x;
        const float2 m0 = maps2[j0], m1 = maps2[j1];
        const float2 m2 = maps2[j2], m3 = maps2[j3];
        const float w1 = v1 ? 1.f : 0.f, w2 = v2 ? 1.f : 0.f, w3 = v3 ? 1.f : 0.f;
        s0 += m0.x*m0.x + w1*m1.x*m1.x + w2*m2.x*m2.x + w3*m3.x*m3.x;
        s1 += m0.y*m0.y + w1*m1.y*m1.y + w2*m2.y*m2.y + w3*m3.y*m3.y;
    }
    const int cpad = (c + 7) & ~7;
    for (int k = c; k < cpad; ++k) al[k] = make_int2(kE2, n);
    diag[n] = make_float2(s0, s1);
}

// ---------------------------------------------------------------------------
// k_off: per ORIGINAL edge j: off[j] = -m_fwd*m_bwd * rsqrt((ds+1)(dt+1))
// Thread kE0 also writes the sentinel zero entry off[kE0].
// ---------------------------------------------------------------------------
__global__ __launch_bounds__(256) void k_off(
    const int* __restrict__ src, const int* __restrict__ dst,
    const float2* __restrict__ maps2, const float2* __restrict__ diag,
    float2* __restrict__ off)
{
    const int j = blockIdx.x * 256 + threadIdx.x;
    if (j >= kE0) {
        if (j == kE0) off[kE0] = make_float2(0.f, 0.f);
        return;
    }
    const float2 ma = maps2[j];
    const float2 mb = maps2[j + kE0];
    const int s = src[j], d = dst[j];
    const float2 ds = diag[s], dt = diag[d];
    off[j] = make_float2(-ma.x * mb.x * rsqrtf((ds.x + 1.0f) * (dt.x + 1.0f)),
                         -ma.y * mb.y * rsqrtf((ds.y + 1.0f) * (dt.y + 1.0f)));
}

// ---------------------------------------------------------------------------
// k_gather: one wave per node; lane covers (d = lane>>5, h4 = (lane&31)*4)
// 8-wide mask-free MLP loop, ALL NAMED SCALARS (no private arrays —
// avoids AMDGPUPromoteAlloca putting them in LDS, the round-8 regression).
// ---------------------------------------------------------------------------
__global__ __launch_bounds__(256) void k_gather(
    const f16* __restrict__ xb, const float* __restrict__ diag,
    const float2* __restrict__ off, const int* __restrict__ cnt,
    const int2* __restrict__ adj, float* __restrict__ y)
{
    const int node = blockIdx.x * 4 + (threadIdx.x >> 6);
    const int lane = threadIdx.x & 63;
    const int d    = lane >> 5;
    const int h4   = (lane & 31) << 2;
    const size_t rowoff = ((size_t)node * 2 + d) * 128 + h4;
    const f16x4 own = *(const f16x4*)(xb + rowoff);
    const float dv  = diag[node * 2 + d];
    const float dg  = dv / (dv + 1.0f);             // dis*diag*dis exactly
    f32x4 acc = {dg * (float)own[0], dg * (float)own[1],
                 dg * (float)own[2], dg * (float)own[3]};
    int c = cnt[node];
    if (c > kCAP) c = kCAP;
    const int2* al = adj + (size_t)node * kCAP;

    for (int k = 0; k < c; k += 8) {
        const int4 ea = *(const int4*)(al + k);
        const int4 eb = *(const int4*)(al + k + 2);
        const int4 ec = *(const int4*)(al + k + 4);
        const int4 ed = *(const int4*)(al + k + 6);
        const int j0 = ea.x, n0 = ea.y, j1 = ea.z, n1 = ea.w;
        const int j2 = eb.x, n2 = eb.y, j3 = eb.z, n3 = eb.w;
        const int j4 = ec.x, n4 = ec.y, j5 = ec.z, n5 = ec.w;
        const int j6 = ed.x, n6 = ed.y, j7 = ed.z, n7 = ed.w;
        const float2 q0 = off[j0 - (j0 >= kE0 ? kE0 : 0)];
        const float2 q1 = off[j1 - (j1 >= kE0 ? kE0 : 0)];
        const float2 q2 = off[j2 - (j2 >= kE0 ? kE0 : 0)];
        const float2 q3 = off[j3 - (j3 >= kE0 ? kE0 : 0)];
        const float2 q4 = off[j4 - (j4 >= kE0 ? kE0 : 0)];
        const float2 q5 = off[j5 - (j5 >= kE0 ? kE0 : 0)];
        const float2 q6 = off[j6 - (j6 >= kE0 ? kE0 : 0)];
        const float2 q7 = off[j7 - (j7 >= kE0 ? kE0 : 0)];
        const f16x4 w0 = *(const f16x4*)(xb + ((size_t)n0 * 2 + d) * 128 + h4);
        const f16x4 w1 = *(const f16x4*)(xb + ((size_t)n1 * 2 + d) * 128 + h4);
        const f16x4 w2 = *(const f16x4*)(xb + ((size_t)n2 * 2 + d) * 128 + h4);
        const f16x4 w3 = *(const f16x4*)(xb + ((size_t)n3 * 2 + d) * 128 + h4);
        const f16x4 w4 = *(const f16x4*)(xb + ((size_t)n4 * 2 + d) * 128 + h4);
        const f16x4 w5 = *(const f16x4*)(xb + ((size_t)n5 * 2 + d) * 128 + h4);
        const f16x4 w6 = *(const f16x4*)(xb + ((size_t)n6 * 2 + d) * 128 + h4);
        const f16x4 w7 = *(const f16x4*)(xb + ((size_t)n7 * 2 + d) * 128 + h4);
        const float o0 = d ? q0.y : q0.x;
        const float o1 = d ? q1.y : q1.x;
        const float o2 = d ? q2.y : q2.x;
        const float o3 = d ? q3.y : q3.x;
        const float o4 = d ? q4.y : q4.x;
        const float o5 = d ? q5.y : q5.x;
        const float o6 = d ? q6.y : q6.x;
        const float o7 = d ? q7.y : q7.x;
        #pragma unroll
        for (int i = 0; i < 4; ++i) {
            float s = o0 * (float)w0[i] + o1 * (float)w1[i];
            s += o2 * (float)w2[i] + o3 * (float)w3[i];
            s += o4 * (float)w4[i] + o5 * (float)w5[i];
            s += o6 * (float)w6[i] + o7 * (float)w7[i];
            acc[i] += s;
        }
    }
    __builtin_nontemporal_store(acc, (f32x4*)(y + rowoff));
}

// ---------------------------------------------------------------------------
extern "C" void kernel_launch(void* const* d_in, const int* in_sizes, int n_in,
                              void* d_out, int out_size, void* d_ws, size_t ws_size,
                              hipStream_t stream)
{
    const float* x   = (const float*)d_in[1];
    const int*   src = (const int*)d_in[2];
    const int*   dst = (const int*)d_in[3];
    const float* Wsh = (const float*)d_in[4];
    const float* Wl  = (const float*)d_in[5];
    const float* Wr  = (const float*)d_in[6];

    char* ws = (char*)d_ws;
    f16*    xb    = (f16*)   (ws + 0);           // 25,600,000 B
    float4* ab    = (float4*)(ws + 25600000);    //    800,000 B
    float2* maps2 = (float2*)(ws + 26400000);    //  3,200,000 B (2*E0 float2)
    float2* off   = (float2*)(ws + 29600000);    //  1,600,008 B (kE0+1 entries)
    float2* diag  = (float2*)(ws + 31200016);    //    400,000 B
    int*    cnt   = (int*)   (ws + 31600016);    //    200,000 B
    int2*   adj   = (int2*)  (ws + 31800016);    // 12,800,000 B (kCAP=32)
    f16*    Wrh   = (f16*)   (ws + 44600016);    //     32,768 B

    (void)hipMemsetAsync(cnt, 0, 200000, stream);

    k_wrh   <<<64,    256, 0, stream>>>(Wr, Wrh);
    k_ab    <<<12500, 256, 0, stream>>>(x, Wsh, ab);
    k_node  <<<1563,  256, 0, stream>>>(x, Wl, Wrh, xb);
    k_edge1 <<<1563,  256, 0, stream>>>(src, dst, ab, maps2, cnt, adj);
    k_diag  <<<196,   256, 0, stream>>>(cnt, adj, maps2, diag);
    k_off   <<<783,   256, 0, stream>>>(src, dst, maps2, diag, off);
    k_gather<<<12500, 256, 0, stream>>>(xb, (const float*)diag, off, cnt, adj, (float*)d_out);
}

// Round 11
// 137.257 us; speedup vs baseline: 1.0922x; 1.0922x over previous
//
#include <hip/hip_runtime.h>

static constexpr int kN   = 50000;    // nodes
static constexpr int kNR  = 100000;   // N*D rows
static constexpr int kE0  = 200000;   // original edges
static constexpr int kE2  = 400000;   // directed edges
static constexpr int kCAP = 32;       // adjacency capacity per node (Poisson(8): P(>=32)~7e-11)

typedef _Float16 f16;
typedef f16   f16x8 __attribute__((ext_vector_type(8)));
typedef f16   f16x4 __attribute__((ext_vector_type(4)));
typedef float f32x4 __attribute__((ext_vector_type(4)));

// ---------------------------------------------------------------------------
// k_wrh: one-shot conversions: W_right -> f16 (16384), and block 0 also
// builds Wsh8[8][128] f16: j = (p<<1)|h, p in {a0,a1,b0,b1}, h = K-half.
// ---------------------------------------------------------------------------
__global__ __launch_bounds__(256) void k_wrh(
    const float* __restrict__ Wr, const float* __restrict__ Wsh,
    f16* __restrict__ Wrh, f16* __restrict__ Wsh8)
{
    const int i = blockIdx.x * 256 + threadIdx.x;   // 16384 elements
    Wrh[i] = (f16)Wr[i];
    if (blockIdx.x == 0) {
        #pragma unroll
        for (int q = 0; q < 4; ++q) {
            const int idx = q * 256 + threadIdx.x;  // j*128 + k
            const int j = idx >> 7, k = idx & 127;
            // src = b?256:0 + a1?512:0 + half*128
            const int srcoff = ((j >> 2) ? 256 : 0) + (((j >> 1) & 1) ? 512 : 0) + ((j & 1) ? 128 : 0);
            Wsh8[idx] = (f16)Wsh[srcoff + k];
        }
    }
}

// ---------------------------------------------------------------------------
// k_node (fused): per block = 32 nodes (64 rows).
//  - stage RAW x rows as f16 into LDS (one float4 load/thread/iter)
//  - pass 1 (ab): mfma(x_frag, Wsh8_frag) -> C[x_row][j];
//      ab_p[n] = C[2n][2p] + C[2n+1][2p+1]  via shfl_xor(1)
//  - pass 2 (GEMM): tfr = cS*x[r] + cP*x[r^1] (packed f16 blend in regs),
//      mfma(Wr_frag, tfr) -> lane holds 4 consecutive c of node-row ->
//      direct packed f16x4 store of xb (no repack)
// ---------------------------------------------------------------------------
__global__ __launch_bounds__(256) void k_node(
    const float* __restrict__ x, const float* __restrict__ Wl,
    const f16* __restrict__ Wrh, const f16* __restrict__ Wsh8,
    f16* __restrict__ xb, float* __restrict__ abf)
{
    __shared__ f16 Al[64][136];    // raw x rows (+8 pad)

    const int t   = threadIdx.x;
    const int blk = blockIdx.x;
    const float wl00 = Wl[0], wl01 = Wl[1], wl10 = Wl[2], wl11 = Wl[3];
    const int w = t >> 6, lane = t & 63;

    // stage raw x -> LDS f16 (packed b64 writes)
    #pragma unroll
    for (int i = 0; i < 8; ++i) {
        const int f4   = i * 256 + t;        // float4 index in 64x128 tile
        const int row  = f4 >> 5;            // 0..63
        const int h4   = (f4 & 31) << 2;     // 0..124
        const int grow = blk * 64 + row;
        float4 xo = make_float4(0.f, 0.f, 0.f, 0.f);
        if (grow < kNR) xo = *(const float4*)(x + (size_t)grow * 128 + h4);
        f16x4 tv;
        tv[0] = (f16)xo.x; tv[1] = (f16)xo.y; tv[2] = (f16)xo.z; tv[3] = (f16)xo.w;
        *(f16x4*)&Al[row][h4] = tv;
    }
    __syncthreads();

    const int lr = lane & 15, lk = lane >> 4;

    // load x fragments: own row r = 16w+lr and partner row r^1
    f16x8 xfr[4], xpr[4];
    #pragma unroll
    for (int kk = 0; kk < 4; ++kk) {
        xfr[kk] = *(const f16x8*)&Al[16 * w + lr][kk * 32 + lk * 8];
        xpr[kk] = *(const f16x8*)&Al[16 * w + (lr ^ 1)][kk * 32 + lk * 8];
    }

    // ---- pass 1: ab via MFMA (cols 8..15 zeroed) ----
    f32x4 cab = {0.f, 0.f, 0.f, 0.f};
    #pragma unroll
    for (int kk = 0; kk < 4; ++kk) {
        f16x8 bw = {};
        if (lr < 8) bw = *(const f16x8*)(Wsh8 + lr * 128 + kk * 32 + lk * 8);
        cab = __builtin_amdgcn_mfma_f32_16x16x32_f16(xfr[kk], bw, cab, 0, 0, 0);
    }
    // epilogue: lane(col=lr, hi=lk) holds C rows 16w+4*lk+{0..3}
    #pragma unroll
    for (int tt = 0; tt < 2; ++tt) {
        const float hi_reg  = cab[2 * tt + 1];
        const float partner = __shfl_xor(hi_reg, 1);   // C[2n+1][lr^1]
        const float val     = cab[2 * tt] + partner;   // valid on even lr
        if (!(lr & 1) && lr < 8) {
            const int node = blk * 32 + 8 * w + 2 * lk + tt;
            if (node < kN) abf[node * 4 + (lr >> 1)] = val;
        }
    }

    // ---- pass 2: blend tmp fragments (packed f16) + main GEMM ----
    const int dp = lr & 1;
    const f16 cS = (f16)(dp ? wl11 : wl00);   // coeff on x[r]
    const f16 cP = (f16)(dp ? wl10 : wl01);   // coeff on x[r^1]
    const f16x8 cS8 = {cS, cS, cS, cS, cS, cS, cS, cS};
    const f16x8 cP8 = {cP, cP, cP, cP, cP, cP, cP, cP};
    f16x8 tfr[4];
    #pragma unroll
    for (int kk = 0; kk < 4; ++kk)
        tfr[kk] = cS8 * xfr[kk] + cP8 * xpr[kk];

    const int grow = blk * 64 + 16 * w + lr;   // node-row this lane outputs
    #pragma unroll
    for (int j = 0; j < 8; ++j) {
        f32x4 acc = {0.f, 0.f, 0.f, 0.f};
        #pragma unroll
        for (int kk = 0; kk < 4; ++kk) {
            const f16x8 wfr = *(const f16x8*)(Wrh + (size_t)(j * 16 + lr) * 128 + kk * 32 + lk * 8);
            acc = __builtin_amdgcn_mfma_f32_16x16x32_f16(wfr, tfr[kk], acc, 0, 0, 0);
        }
        f16x4 ov;
        ov[0] = (f16)(-acc[0]); ov[1] = (f16)(-acc[1]);
        ov[2] = (f16)(-acc[2]); ov[3] = (f16)(-acc[3]);
        if (grow < kNR)
            *(f16x4*)(xb + (size_t)grow * 128 + j * 16 + lk * 4) = ov;
    }
}

// ---------------------------------------------------------------------------
// k_edge1: per DIRECTED edge j in [0,2*E0): maps2[j] = tanh(a[row]+b[col]),
// adjacency append (1 atomic per directed edge; no diag atomics).
// ---------------------------------------------------------------------------
__global__ __launch_bounds__(256) void k_edge1(
    const int* __restrict__ src, const int* __restrict__ dst,
    const float4* __restrict__ ab, float2* __restrict__ maps2,
    int* __restrict__ cnt, int2* __restrict__ adj)
{
    const int j = blockIdx.x * 256 + threadIdx.x;
    if (j >= kE2) return;
    const bool fwd = j < kE0;
    const int o = fwd ? j : j - kE0;
    const int s = src[o], d = dst[o];
    const int row = fwd ? s : d;
    const int col = fwd ? d : s;
    const float4 ar = ab[row], ac = ab[col];
    const float m0 = tanhf(ar.x + ac.z);
    const float m1 = tanhf(ar.y + ac.w);
    maps2[j] = make_float2(m0, m1);
    const int p = atomicAdd(&cnt[row], 1);
    if (p < kCAP) adj[(size_t)row * kCAP + p] = make_int2(j, col);
}

// ---------------------------------------------------------------------------
// k_diag: 16 lanes per node. Parallel slot gathers (slots sl, sl+16),
// 4-step shfl reduce; sentinel-pads adjacency to multiple of 8.
// ---------------------------------------------------------------------------
__global__ __launch_bounds__(256) void k_diag(
    const int* __restrict__ cnt, int2* __restrict__ adj,
    const float2* __restrict__ maps2, float2* __restrict__ diag)
{
    const int node = blockIdx.x * 16 + (threadIdx.x >> 4);
    const int sl   = threadIdx.x & 15;
    if (node >= kN) return;
    int c = cnt[node];
    if (c > kCAP) c = kCAP;
    int2* al = adj + (size_t)node * kCAP;
    const int2 e0 = al[sl];
    const int2 e1 = al[sl + 16];
    float s0 = 0.f, s1 = 0.f;
    if (sl < c)      { const float2 m = maps2[e0.x]; s0 += m.x * m.x; s1 += m.y * m.y; }
    if (sl + 16 < c) { const float2 m = maps2[e1.x]; s0 += m.x * m.x; s1 += m.y * m.y; }
    const int cpad = (c + 7) & ~7;
    if (sl >= c && sl < cpad)           al[sl]      = make_int2(kE2, node);
    if (sl + 16 >= c && sl + 16 < cpad) al[sl + 16] = make_int2(kE2, node);
    #pragma unroll
    for (int o = 8; o > 0; o >>= 1) {
        s0 += __shfl_xor(s0, o);
        s1 += __shfl_xor(s1, o);
    }
    if (sl == 0) diag[node] = make_float2(s0, s1);
}

// ---------------------------------------------------------------------------
// k_off: per ORIGINAL edge j: off[j] = -m_fwd*m_bwd * rsqrt((ds+1)(dt+1))
// Thread kE0 also writes the sentinel zero entry off[kE0].
// ---------------------------------------------------------------------------
__global__ __launch_bounds__(256) void k_off(
    const int* __restrict__ src, const int* __restrict__ dst,
    const float2* __restrict__ maps2, const float2* __restrict__ diag,
    float2* __restrict__ off)
{
    const int j = blockIdx.x * 256 + threadIdx.x;
    if (j >= kE0) {
        if (j == kE0) off[kE0] = make_float2(0.f, 0.f);
        return;
    }
    const float2 ma = maps2[j];
    const float2 mb = maps2[j + kE0];
    const int s = src[j], d = dst[j];
    const float2 ds = diag[s], dt = diag[d];
    off[j] = make_float2(-ma.x * mb.x * rsqrtf((ds.x + 1.0f) * (dt.x + 1.0f)),
                         -ma.y * mb.y * rsqrtf((ds.y + 1.0f) * (dt.y + 1.0f)));
}

// ---------------------------------------------------------------------------
// k_gather: one wave per node; lane covers (d = lane>>5, h4 = (lane&31)*4)
// 8-wide mask-free MLP loop, ALL NAMED SCALARS (no private arrays —
// avoids AMDGPUPromoteAlloca putting them in LDS, the round-8 regression).
// ---------------------------------------------------------------------------
__global__ __launch_bounds__(256) void k_gather(
    const f16* __restrict__ xb, const float* __restrict__ diag,
    const float2* __restrict__ off, const int* __restrict__ cnt,
    const int2* __restrict__ adj, float* __restrict__ y)
{
    const int node = blockIdx.x * 4 + (threadIdx.x >> 6);
    const int lane = threadIdx.x & 63;
    const int d    = lane >> 5;
    const int h4   = (lane & 31) << 2;
    const size_t rowoff = ((size_t)node * 2 + d) * 128 + h4;
    const f16x4 own = *(const f16x4*)(xb + rowoff);
    const float dv  = diag[node * 2 + d];
    const float dg  = dv / (dv + 1.0f);             // dis*diag*dis exactly
    f32x4 acc = {dg * (float)own[0], dg * (float)own[1],
                 dg * (float)own[2], dg * (float)own[3]};
    int c = cnt[node];
    if (c > kCAP) c = kCAP;
    const int2* al = adj + (size_t)node * kCAP;

    for (int k = 0; k < c; k += 8) {
        const int4 ea = *(const int4*)(al + k);
        const int4 eb = *(const int4*)(al + k + 2);
        const int4 ec = *(const int4*)(al + k + 4);
        const int4 ed = *(const int4*)(al + k + 6);
        const int j0 = ea.x, n0 = ea.y, j1 = ea.z, n1 = ea.w;
        const int j2 = eb.x, n2 = eb.y, j3 = eb.z, n3 = eb.w;
        const int j4 = ec.x, n4 = ec.y, j5 = ec.z, n5 = ec.w;
        const int j6 = ed.x, n6 = ed.y, j7 = ed.z, n7 = ed.w;
        const float2 q0 = off[j0 - (j0 >= kE0 ? kE0 : 0)];
        const float2 q1 = off[j1 - (j1 >= kE0 ? kE0 : 0)];
        const float2 q2 = off[j2 - (j2 >= kE0 ? kE0 : 0)];
        const float2 q3 = off[j3 - (j3 >= kE0 ? kE0 : 0)];
        const float2 q4 = off[j4 - (j4 >= kE0 ? kE0 : 0)];
        const float2 q5 = off[j5 - (j5 >= kE0 ? kE0 : 0)];
        const float2 q6 = off[j6 - (j6 >= kE0 ? kE0 : 0)];
        const float2 q7 = off[j7 - (j7 >= kE0 ? kE0 : 0)];
        const f16x4 w0 = *(const f16x4*)(xb + ((size_t)n0 * 2 + d) * 128 + h4);
        const f16x4 w1 = *(const f16x4*)(xb + ((size_t)n1 * 2 + d) * 128 + h4);
        const f16x4 w2 = *(const f16x4*)(xb + ((size_t)n2 * 2 + d) * 128 + h4);
        const f16x4 w3 = *(const f16x4*)(xb + ((size_t)n3 * 2 + d) * 128 + h4);
        const f16x4 w4 = *(const f16x4*)(xb + ((size_t)n4 * 2 + d) * 128 + h4);
        const f16x4 w5 = *(const f16x4*)(xb + ((size_t)n5 * 2 + d) * 128 + h4);
        const f16x4 w6 = *(const f16x4*)(xb + ((size_t)n6 * 2 + d) * 128 + h4);
        const f16x4 w7 = *(const f16x4*)(xb + ((size_t)n7 * 2 + d) * 128 + h4);
        const float o0 = d ? q0.y : q0.x;
        const float o1 = d ? q1.y : q1.x;
        const float o2 = d ? q2.y : q2.x;
        const float o3 = d ? q3.y : q3.x;
        const float o4 = d ? q4.y : q4.x;
        const float o5 = d ? q5.y : q5.x;
        const float o6 = d ? q6.y : q6.x;
        const float o7 = d ? q7.y : q7.x;
        #pragma unroll
        for (int i = 0; i < 4; ++i) {
            float s = o0 * (float)w0[i] + o1 * (float)w1[i];
            s += o2 * (float)w2[i] + o3 * (float)w3[i];
            s += o4 * (float)w4[i] + o5 * (float)w5[i];
            s += o6 * (float)w6[i] + o7 * (float)w7[i];
            acc[i] += s;
        }
    }
    __builtin_nontemporal_store(acc, (f32x4*)(y + rowoff));
}

// ---------------------------------------------------------------------------
extern "C" void kernel_launch(void* const* d_in, const int* in_sizes, int n_in,
                              void* d_out, int out_size, void* d_ws, size_t ws_size,
                              hipStream_t stream)
{
    const float* x   = (const float*)d_in[1];
    const int*   src = (const int*)d_in[2];
    const int*   dst = (const int*)d_in[3];
    const float* Wsh = (const float*)d_in[4];
    const float* Wl  = (const float*)d_in[5];
    const float* Wr  = (const float*)d_in[6];

    char* ws = (char*)d_ws;
    f16*    xb    = (f16*)   (ws + 0);           // 25,600,000 B
    float4* ab    = (float4*)(ws + 25600000);    //    800,000 B
    float2* maps2 = (float2*)(ws + 26400000);    //  3,200,000 B (2*E0 float2)
    float2* off   = (float2*)(ws + 29600000);    //  1,600,008 B (kE0+1 entries)
    float2* diag  = (float2*)(ws + 31200016);    //    400,000 B
    int*    cnt   = (int*)   (ws + 31600016);    //    200,000 B
    int2*   adj   = (int2*)  (ws + 31800016);    // 12,800,000 B (kCAP=32)
    f16*    Wrh   = (f16*)   (ws + 44600016);    //     32,768 B
    f16*    Wsh8  = (f16*)   (ws + 44632784);    //      2,048 B

    (void)hipMemsetAsync(cnt, 0, 200000, stream);

    k_wrh   <<<64,    256, 0, stream>>>(Wr, Wsh, Wrh, Wsh8);
    k_node  <<<1563,  256, 0, stream>>>(x, Wl, Wrh, Wsh8, xb, (float*)ab);
    k_edge1 <<<1563,  256, 0, stream>>>(src, dst, ab, maps2, cnt, adj);
    k_diag  <<<3125,  256, 0, stream>>>(cnt, adj, maps2, diag);
    k_off   <<<783,   256, 0, stream>>>(src, dst, maps2, diag, off);
    k_gather<<<12500, 256, 0, stream>>>(xb, (const float*)diag, off, cnt, adj, (float*)d_out);
}

// Round 13
// 134.983 us; speedup vs baseline: 1.1106x; 1.0168x over previous
//
#include <hip/hip_runtime.h>

static constexpr int kN   = 50000;    // nodes
static constexpr int kNR  = 100000;   // N*D rows
static constexpr int kE0  = 200000;   // original edges
static constexpr int kE2  = 400000;   // directed edges
static constexpr int kCAP = 32;       // adjacency capacity per node (Poisson(8): P(>=32)~7e-11)

typedef _Float16 f16;
typedef f16   f16x8 __attribute__((ext_vector_type(8)));
typedef f16   f16x4 __attribute__((ext_vector_type(4)));
typedef float f32x4 __attribute__((ext_vector_type(4)));

// ---------------------------------------------------------------------------
// k_wrh (fused init): zero cnt; convert W_right -> f16; block 0 builds
// Wsh8[8][128] f16: j = (p<<1)|h, p in {a0,a1,b0,b1}, h = K-half.
// grid = 196 blocks (50176 threads >= kN and >= 16384)
// ---------------------------------------------------------------------------
__global__ __launch_bounds__(256) void k_wrh(
    const float* __restrict__ Wr, const float* __restrict__ Wsh,
    f16* __restrict__ Wrh, f16* __restrict__ Wsh8, int* __restrict__ cnt)
{
    const int i = blockIdx.x * 256 + threadIdx.x;
    if (i < kN) cnt[i] = 0;
    if (i < 16384) Wrh[i] = (f16)Wr[i];
    if (blockIdx.x == 0) {
        #pragma unroll
        for (int q = 0; q < 4; ++q) {
            const int idx = q * 256 + threadIdx.x;  // j*128 + k
            const int j = idx >> 7, k = idx & 127;
            const int srcoff = ((j >> 2) ? 256 : 0) + (((j >> 1) & 1) ? 512 : 0) + ((j & 1) ? 128 : 0);
            Wsh8[idx] = (f16)Wsh[srcoff + k];
        }
    }
}

// ---------------------------------------------------------------------------
// k_node (fused): per block = 32 nodes (64 rows).
//  - stage RAW x rows as f16 into LDS (b128 writes, 4 iters)
//  - pass 1 (ab): mfma(x_frag, Wsh8_frag) -> C[x_row][j];
//      ab_p[n] = C[2n][2p] + C[2n+1][2p+1]  via shfl_xor(1)
//  - pass 2 (GEMM): tfr = cS*x[r] + cP*x[r^1] (packed f16 blend),
//      mfma(Wr_frag, tfr) with Wrh fragments PREFETCHED one j ahead ->
//      lane holds 4 consecutive c of node-row -> direct f16x4 store
// ---------------------------------------------------------------------------
__global__ __launch_bounds__(256) void k_node(
    const float* __restrict__ x, const float* __restrict__ Wl,
    const f16* __restrict__ Wrh, const f16* __restrict__ Wsh8,
    f16* __restrict__ xb, float* __restrict__ abf)
{
    __shared__ f16 Al[64][136];    // raw x rows (+8 pad)

    const int t   = threadIdx.x;
    const int blk = blockIdx.x;
    const float wl00 = Wl[0], wl01 = Wl[1], wl10 = Wl[2], wl11 = Wl[3];
    const int w = t >> 6, lane = t & 63;

    // stage raw x -> LDS f16 (b128 writes: 8 floats -> f16x8 per thread/iter)
    #pragma unroll
    for (int i = 0; i < 4; ++i) {
        const int f8   = i * 256 + t;        // f16x8-chunk index in 64x128 tile
        const int row  = f8 >> 4;            // 0..63
        const int c8   = (f8 & 15) << 3;     // 0..120
        const int grow = blk * 64 + row;
        float4 xa = make_float4(0.f, 0.f, 0.f, 0.f), xc = xa;
        if (grow < kNR) {
            xa = *(const float4*)(x + (size_t)grow * 128 + c8);
            xc = *(const float4*)(x + (size_t)grow * 128 + c8 + 4);
        }
        f16x8 tv;
        tv[0] = (f16)xa.x; tv[1] = (f16)xa.y; tv[2] = (f16)xa.z; tv[3] = (f16)xa.w;
        tv[4] = (f16)xc.x; tv[5] = (f16)xc.y; tv[6] = (f16)xc.z; tv[7] = (f16)xc.w;
        *(f16x8*)&Al[row][c8] = tv;
    }
    __syncthreads();

    const int lr = lane & 15, lk = lane >> 4;

    // load x fragments: own row r = 16w+lr and partner row r^1
    f16x8 xfr[4], xpr[4];
    #pragma unroll
    for (int kk = 0; kk < 4; ++kk) {
        xfr[kk] = *(const f16x8*)&Al[16 * w + lr][kk * 32 + lk * 8];
        xpr[kk] = *(const f16x8*)&Al[16 * w + (lr ^ 1)][kk * 32 + lk * 8];
    }

    // ---- pass 1: ab via MFMA (cols 8..15 zeroed) ----
    f32x4 cab = {0.f, 0.f, 0.f, 0.f};
    #pragma unroll
    for (int kk = 0; kk < 4; ++kk) {
        f16x8 bw = {};
        if (lr < 8) bw = *(const f16x8*)(Wsh8 + lr * 128 + kk * 32 + lk * 8);
        cab = __builtin_amdgcn_mfma_f32_16x16x32_f16(xfr[kk], bw, cab, 0, 0, 0);
    }
    #pragma unroll
    for (int tt = 0; tt < 2; ++tt) {
        const float hi_reg  = cab[2 * tt + 1];
        const float partner = __shfl_xor(hi_reg, 1);   // C[2n+1][lr^1]
        const float val     = cab[2 * tt] + partner;   // valid on even lr
        if (!(lr & 1) && lr < 8) {
            const int node = blk * 32 + 8 * w + 2 * lk + tt;
            if (node < kN) abf[node * 4 + (lr >> 1)] = val;
        }
    }

    // ---- pass 2: blend tmp fragments (packed f16) + main GEMM ----
    const int dp = lr & 1;
    const f16 cS = (f16)(dp ? wl11 : wl00);   // coeff on x[r]
    const f16 cP = (f16)(dp ? wl10 : wl01);   // coeff on x[r^1]
    const f16x8 cS8 = {cS, cS, cS, cS, cS, cS, cS, cS};
    const f16x8 cP8 = {cP, cP, cP, cP, cP, cP, cP, cP};
    f16x8 tfr[4];
    #pragma unroll
    for (int kk = 0; kk < 4; ++kk)
        tfr[kk] = cS8 * xfr[kk] + cP8 * xpr[kk];

    const int grow = blk * 64 + 16 * w + lr;   // node-row this lane outputs

    // prefetch Wrh fragments for j=0
    f16x8 wf0[4], wf1[4];
    #pragma unroll
    for (int kk = 0; kk < 4; ++kk)
        wf0[kk] = *(const f16x8*)(Wrh + (size_t)(0 * 16 + lr) * 128 + kk * 32 + lk * 8);

    #pragma unroll
    for (int j = 0; j < 8; ++j) {
        // issue next-j Wrh loads before this j's MFMAs (latency overlap)
        if (j < 7) {
            #pragma unroll
            for (int kk = 0; kk < 4; ++kk)
                wf1[kk] = *(const f16x8*)(Wrh + (size_t)((j + 1) * 16 + lr) * 128 + kk * 32 + lk * 8);
        }
        f32x4 acc = {0.f, 0.f, 0.f, 0.f};
        #pragma unroll
        for (int kk = 0; kk < 4; ++kk)
            acc = __builtin_amdgcn_mfma_f32_16x16x32_f16(wf0[kk], tfr[kk], acc, 0, 0, 0);
        f16x4 ov;
        ov[0] = (f16)(-acc[0]); ov[1] = (f16)(-acc[1]);
        ov[2] = (f16)(-acc[2]); ov[3] = (f16)(-acc[3]);
        if (grow < kNR)
            *(f16x4*)(xb + (size_t)grow * 128 + j * 16 + lk * 4) = ov;
        #pragma unroll
        for (int kk = 0; kk < 4; ++kk)
            wf0[kk] = wf1[kk];
    }
}

// ---------------------------------------------------------------------------
// k_edge1: per DIRECTED edge j in [0,2*E0): maps2[j] = tanh(a[row]+b[col]),
// adjacency append (1 atomic per directed edge; no diag atomics).
// ---------------------------------------------------------------------------
__global__ __launch_bounds__(256) void k_edge1(
    const int* __restrict__ src, const int* __restrict__ dst,
    const float4* __restrict__ ab, float2* __restrict__ maps2,
    int* __restrict__ cnt, int2* __restrict__ adj)
{
    const int j = blockIdx.x * 256 + threadIdx.x;
    if (j >= kE2) return;
    const bool fwd = j < kE0;
    const int o = fwd ? j : j - kE0;
    const int s = src[o], d = dst[o];
    const int row = fwd ? s : d;
    const int col = fwd ? d : s;
    const float4 ar = ab[row], ac = ab[col];
    const float m0 = tanhf(ar.x + ac.z);
    const float m1 = tanhf(ar.y + ac.w);
    maps2[j] = make_float2(m0, m1);
    const int p = atomicAdd(&cnt[row], 1);
    if (p < kCAP) adj[(size_t)row * kCAP + p] = make_int2(j, col);
}

// ---------------------------------------------------------------------------
// k_diag: 16 lanes per node. Parallel slot gathers (slots sl, sl+16),
// 4-step shfl reduce; sentinel-pads adjacency to multiple of 8.
// ---------------------------------------------------------------------------
__global__ __launch_bounds__(256) void k_diag(
    const int* __restrict__ cnt, int2* __restrict__ adj,
    const float2* __restrict__ maps2, float2* __restrict__ diag)
{
    const int node = blockIdx.x * 16 + (threadIdx.x >> 4);
    const int sl   = threadIdx.x & 15;
    if (node >= kN) return;
    int c = cnt[node];
    if (c > kCAP) c = kCAP;
    int2* al = adj + (size_t)node * kCAP;
    const int2 e0 = al[sl];
    const int2 e1 = al[sl + 16];
    float s0 = 0.f, s1 = 0.f;
    if (sl < c)      { const float2 m = maps2[e0.x]; s0 += m.x * m.x; s1 += m.y * m.y; }
    if (sl + 16 < c) { const float2 m = maps2[e1.x]; s0 += m.x * m.x; s1 += m.y * m.y; }
    const int cpad = (c + 7) & ~7;
    if (sl >= c && sl < cpad)           al[sl]      = make_int2(kE2, node);
    if (sl + 16 >= c && sl + 16 < cpad) al[sl + 16] = make_int2(kE2, node);
    #pragma unroll
    for (int o = 8; o > 0; o >>= 1) {
        s0 += __shfl_xor(s0, o);
        s1 += __shfl_xor(s1, o);
    }
    if (sl == 0) diag[node] = make_float2(s0, s1);
}

// ---------------------------------------------------------------------------
// k_off: per ORIGINAL edge j: off[j] = -m_fwd*m_bwd * rsqrt((ds+1)(dt+1))
// Thread kE0 also writes the sentinel zero entry off[kE0].
// ---------------------------------------------------------------------------
__global__ __launch_bounds__(256) void k_off(
    const int* __restrict__ src, const int* __restrict__ dst,
    const float2* __restrict__ maps2, const float2* __restrict__ diag,
    float2* __restrict__ off)
{
    const int j = blockIdx.x * 256 + threadIdx.x;
    if (j >= kE0) {
        if (j == kE0) off[kE0] = make_float2(0.f, 0.f);
        return;
    }
    const float2 ma = maps2[j];
    const float2 mb = maps2[j + kE0];
    const int s = src[j], d = dst[j];
    const float2 ds = diag[s], dt = diag[d];
    off[j] = make_float2(-ma.x * mb.x * rsqrtf((ds.x + 1.0f) * (dt.x + 1.0f)),
                         -ma.y * mb.y * rsqrtf((ds.y + 1.0f) * (dt.y + 1.0f)));
}

// ---------------------------------------------------------------------------
// k_gather: one wave per node; lane covers (d = lane>>5, h4 = (lane&31)*4)
// 8-wide mask-free MLP loop, named scalars; neighbor accumulation in
// PACKED f16 (v_pk_fma_f16, 2 ops/neighbor) -> f32 merge at the end.
// ---------------------------------------------------------------------------
__global__ __launch_bounds__(256) void k_gather(
    const f16* __restrict__ xb, const float* __restrict__ diag,
    const float2* __restrict__ off, const int* __restrict__ cnt,
    const int2* __restrict__ adj, float* __restrict__ y)
{
    const int node = blockIdx.x * 4 + (threadIdx.x >> 6);
    const int lane = threadIdx.x & 63;
    const int d    = lane >> 5;
    const int h4   = (lane & 31) << 2;
    const size_t rowoff = ((size_t)node * 2 + d) * 128 + h4;
    const f16x4 own = *(const f16x4*)(xb + rowoff);
    const float dv  = diag[node * 2 + d];
    const float dg  = dv / (dv + 1.0f);             // dis*diag*dis exactly
    f32x4 acc = {dg * (float)own[0], dg * (float)own[1],
                 dg * (float)own[2], dg * (float)own[3]};
    int c = cnt[node];
    if (c > kCAP) c = kCAP;
    const int2* al = adj + (size_t)node * kCAP;

    f16x4 acch = {(f16)0.f, (f16)0.f, (f16)0.f, (f16)0.f};
    for (int k = 0; k < c; k += 8) {
        const int4 ea = *(const int4*)(al + k);
        const int4 eb = *(const int4*)(al + k + 2);
        const int4 ec = *(const int4*)(al + k + 4);
        const int4 ed = *(const int4*)(al + k + 6);
        const int j0 = ea.x, n0 = ea.y, j1 = ea.z, n1 = ea.w;
        const int j2 = eb.x, n2 = eb.y, j3 = eb.z, n3 = eb.w;
        const int j4 = ec.x, n4 = ec.y, j5 = ec.z, n5 = ec.w;
        const int j6 = ed.x, n6 = ed.y, j7 = ed.z, n7 = ed.w;
        const float2 q0 = off[j0 - (j0 >= kE0 ? kE0 : 0)];
        const float2 q1 = off[j1 - (j1 >= kE0 ? kE0 : 0)];
        const float2 q2 = off[j2 - (j2 >= kE0 ? kE0 : 0)];
        const float2 q3 = off[j3 - (j3 >= kE0 ? kE0 : 0)];
        const float2 q4 = off[j4 - (j4 >= kE0 ? kE0 : 0)];
        const float2 q5 = off[j5 - (j5 >= kE0 ? kE0 : 0)];
        const float2 q6 = off[j6 - (j6 >= kE0 ? kE0 : 0)];
        const float2 q7 = off[j7 - (j7 >= kE0 ? kE0 : 0)];
        const f16x4 w0 = *(const f16x4*)(xb + ((size_t)n0 * 2 + d) * 128 + h4);
        const f16x4 w1 = *(const f16x4*)(xb + ((size_t)n1 * 2 + d) * 128 + h4);
        const f16x4 w2 = *(const f16x4*)(xb + ((size_t)n2 * 2 + d) * 128 + h4);
        const f16x4 w3 = *(const f16x4*)(xb + ((size_t)n3 * 2 + d) * 128 + h4);
        const f16x4 w4 = *(const f16x4*)(xb + ((size_t)n4 * 2 + d) * 128 + h4);
        const f16x4 w5 = *(const f16x4*)(xb + ((size_t)n5 * 2 + d) * 128 + h4);
        const f16x4 w6 = *(const f16x4*)(xb + ((size_t)n6 * 2 + d) * 128 + h4);
        const f16x4 w7 = *(const f16x4*)(xb + ((size_t)n7 * 2 + d) * 128 + h4);
        const f16 o0 = (f16)(d ? q0.y : q0.x);
        const f16 o1 = (f16)(d ? q1.y : q1.x);
        const f16 o2 = (f16)(d ? q2.y : q2.x);
        const f16 o3 = (f16)(d ? q3.y : q3.x);
        const f16 o4 = (f16)(d ? q4.y : q4.x);
        const f16 o5 = (f16)(d ? q5.y : q5.x);
        const f16 o6 = (f16)(d ? q6.y : q6.x);
        const f16 o7 = (f16)(d ? q7.y : q7.x);
        const f16x4 o40 = {o0, o0, o0, o0};
        const f16x4 o41 = {o1, o1, o1, o1};
        const f16x4 o42 = {o2, o2, o2, o2};
        const f16x4 o43 = {o3, o3, o3, o3};
        const f16x4 o44 = {o4, o4, o4, o4};
        const f16x4 o45 = {o5, o5, o5, o5};
        const f16x4 o46 = {o6, o6, o6, o6};
        const f16x4 o47 = {o7, o7, o7, o7};
        acch += o40 * w0;   // v_pk_fma_f16 pairs
        acch += o41 * w1;
        acch += o42 * w2;
        acch += o43 * w3;
        acch += o44 * w4;
        acch += o45 * w5;
        acch += o46 * w6;
        acch += o47 * w7;
    }
    acc[0] += (float)acch[0];
    acc[1] += (float)acch[1];
    acc[2] += (float)acch[2];
    acc[3] += (float)acch[3];
    __builtin_nontemporal_store(acc, (f32x4*)(y + rowoff));
}

// ---------------------------------------------------------------------------
extern "C" void kernel_launch(void* const* d_in, const int* in_sizes, int n_in,
                              void* d_out, int out_size, void* d_ws, size_t ws_size,
                              hipStream_t stream)
{
    const float* x   = (const float*)d_in[1];
    const int*   src = (const int*)d_in[2];
    const int*   dst = (const int*)d_in[3];
    const float* Wsh = (const float*)d_in[4];
    const float* Wl  = (const float*)d_in[5];
    const float* Wr  = (const float*)d_in[6];

    char* ws = (char*)d_ws;
    f16*    xb    = (f16*)   (ws + 0);           // 25,600,000 B
    float4* ab    = (float4*)(ws + 25600000);    //    800,000 B
    float2* maps2 = (float2*)(ws + 26400000);    //  3,200,000 B (2*E0 float2)
    float2* off   = (float2*)(ws + 29600000);    //  1,600,008 B (kE0+1 entries)
    float2* diag  = (float2*)(ws + 31200016);    //    400,000 B
    int*    cnt   = (int*)   (ws + 31600016);    //    200,000 B
    int2*   adj   = (int2*)  (ws + 31800016);    // 12,800,000 B (kCAP=32)
    f16*    Wrh   = (f16*)   (ws + 44600016);    //     32,768 B
    f16*    Wsh8  = (f16*)   (ws + 44632784);    //      2,048 B

    k_wrh   <<<196,   256, 0, stream>>>(Wr, Wsh, Wrh, Wsh8, cnt);
    k_node  <<<1563,  256, 0, stream>>>(x, Wl, Wrh, Wsh8, xb, (float*)ab);
    k_edge1 <<<1563,  256, 0, stream>>>(src, dst, ab, maps2, cnt, adj);
    k_diag  <<<3125,  256, 0, stream>>>(cnt, adj, maps2, diag);
    k_off   <<<783,   256, 0, stream>>>(src, dst, maps2, diag, off);
    k_gather<<<12500, 256, 0, stream>>>(xb, (const float*)diag, off, cnt, adj, (float*)d_out);
}